// Round 1
// baseline (973.197 us; speedup 1.0000x reference)
//
#include <hip/hip_runtime.h>
#include <cstdint>

typedef unsigned short u16;
typedef __bf16 bf16x8 __attribute__((ext_vector_type(8)));
typedef float f32x4 __attribute__((ext_vector_type(4)));

#define LN_EPS 1e-5f

__device__ __forceinline__ u16 f2b(float f) {
    union { float f; unsigned int i; } v;
    v.f = f;
    unsigned int u = v.i;
    unsigned int r = (u + 0x7FFFu + ((u >> 16) & 1u)) >> 16;  // RNE
    return (u16)r;
}

// ---------------------------------------------------------------------------
// Prep all layers: WT[z][f][k] = bf16( W[z][k][f] * adj[k][f] ), fp32 in.
// grid (F/64, F/64, L), block 256. LDS transpose for coalescing both ways.
// (unchanged from previous verified version)
// ---------------------------------------------------------------------------
__global__ __launch_bounds__(256) void prep_weights(
    const float* __restrict__ W, const float* __restrict__ adj,
    u16* __restrict__ WT, int F)
{
    __shared__ float tile[64][65];
    const int tid = threadIdx.x;
    const size_t lofs = (size_t)blockIdx.z * F * F;
    const int kb = blockIdx.y * 64;
    const int fb = blockIdx.x * 64;
    const int c  = tid & 63;
    const int r0 = tid >> 6;

#pragma unroll
    for (int i = 0; i < 16; ++i) {
        int kl = r0 + i * 4;
        int k = kb + kl, f = fb + c;
        tile[kl][c] = W[lofs + (size_t)k * F + f] * adj[(size_t)k * F + f];
    }
    __syncthreads();
#pragma unroll
    for (int i = 0; i < 16; ++i) {
        int fl = r0 + i * 4;
        int f = fb + fl, k = kb + c;
        WT[lofs + (size_t)f * F + k] = f2b(tile[c][fl]);
    }
}

// ---------------------------------------------------------------------------
// chain: ALL 5 layers in one launch. Rows are independent through the whole
// net (row-GEMM + per-row LN), so each block owns 64 rows and keeps them
// resident:
//   - A operand (h, bf16) in a 128KB LDS tile, XOR-swizzled chunk^(row&7)
//     so stride-2048B row reads are conflict-free for ds_read_b128.
//   - acc = full 64x1024 fp32 row panel in registers (128/thread).
//   - B (WeffT) fragments loaded straight from global (2MB, L2-resident),
//     double-buffered 8-frag prefetch; no barriers inside the K-loop.
//   - fp32-precision residual spilled to a fp16 global workspace (the one
//     thing that fits neither regs nor LDS); same lane writes then reads
//     the same address one layer later (L2/L3 hit, L1 long since evicted).
//   - LN fully in-block: 16-lane shuffle butterflies + tiny LDS reduce.
// Block: 512 thr = 8 waves; wave w owns cols [128w,128w+128). Grid N/64=256
// -> 1 block/CU (LDS 132.5KB forces it), 2 waves/SIMD.
// ---------------------------------------------------------------------------
__global__ __launch_bounds__(512, 2) void chain(
    const float* __restrict__ X,     // (N,F) fp32 input
    const u16* __restrict__ WT,      // (L,F,K) bf16, f-major
    const float* __restrict__ Bias,  // (L,F) fp32
    _Float16* __restrict__ Hf,       // (N,F) fp16 residual workspace
    float* __restrict__ Out,         // (N,F) fp32 output
    int N, int L)
{
    constexpr int F = 1024;
    constexpr int K = 1024;
    extern __shared__ char smem[];
    u16*   Ab  = (u16*)smem;               // [64][1024] bf16, swizzled (128KB)
    float* wsS = (float*)(smem + 131072);  // [8][64] per-wave row sums
    float* wsQ = (float*)(smem + 133120);  // [8][64] per-wave row sumsq
    float* mr  = (float*)(smem + 135168);  // [64][2] mean,rstd

    const int tid  = threadIdx.x;
    const int w    = tid >> 6;        // wave 0..7 -> col slice
    const int lane = tid & 63;
    const int q    = lane >> 4;       // 0..3
    const int r16  = lane & 15;
    const int s3   = r16 & 7;         // swizzle key for A-frag reads
    const int r0   = blockIdx.x * 64;

    const size_t ff = (size_t)F * K;

    // ---- stage Ab from X (fp32 -> bf16, swizzled), coalesced float4 ----
    {
        const float4* Xv = (const float4*)(X + (size_t)r0 * F);
        for (int i = 0; i < 32; ++i) {
            int e4 = i * 512 + tid;            // 0..16383
            float4 v = Xv[e4];
            int el  = e4 * 4;
            int row = el >> 10;
            int col = el & 1023;
            int chunk = (col >> 3) ^ (row & 7);
            int boff  = row * 2048 + chunk * 16 + (col & 7) * 2;  // 8B aligned
            ushort4 pk;
            pk.x = f2b(v.x); pk.y = f2b(v.y); pk.z = f2b(v.z); pk.w = f2b(v.w);
            *(ushort4*)(smem + boff) = pk;
        }
    }
    __syncthreads();

    // per-lane constant addressing
    int aBase[4];
#pragma unroll
    for (int mi = 0; mi < 4; ++mi) aBase[mi] = (mi * 16 + r16) * 2048;
    unsigned int bOff[8];                       // element offsets into a layer's WT
#pragma unroll
    for (int ni = 0; ni < 8; ++ni)
        bOff[ni] = (unsigned int)(w * 128 + ni * 16 + r16) * K + q * 8;

    for (int l = 0; l < L; ++l) {
        const u16* wt = WT + (size_t)l * ff;

        f32x4 acc[4][8];
        const f32x4 zero = {0.f, 0.f, 0.f, 0.f};
#pragma unroll
        for (int mi = 0; mi < 4; ++mi)
#pragma unroll
            for (int ni = 0; ni < 8; ++ni) acc[mi][ni] = zero;

        // ---- K-loop: barrier-free; B frags direct from L2, dbuf prefetch ----
        bf16x8 bA[8], bB[8];
#pragma unroll
        for (int ni = 0; ni < 8; ++ni)
            bA[ni] = *(const bf16x8*)(wt + bOff[ni]);

        for (int k0 = 0; k0 < K; k0 += 64) {
            // prefetch k0+32
#pragma unroll
            for (int ni = 0; ni < 8; ++ni)
                bB[ni] = *(const bf16x8*)(wt + bOff[ni] + (k0 + 32));
            {
                const int kc = (k0 >> 3) + q;
                bf16x8 af[4];
#pragma unroll
                for (int mi = 0; mi < 4; ++mi)
                    af[mi] = *(const bf16x8*)(smem + aBase[mi] + ((kc ^ s3) << 4));
#pragma unroll
                for (int mi = 0; mi < 4; ++mi)
#pragma unroll
                    for (int ni = 0; ni < 8; ++ni)
                        acc[mi][ni] = __builtin_amdgcn_mfma_f32_16x16x32_bf16(
                            af[mi], bA[ni], acc[mi][ni], 0, 0, 0);
            }
            // prefetch k0+64 (wraps to 0 on last iter; value unused)
            const int kn = (k0 + 64) & (K - 1);
#pragma unroll
            for (int ni = 0; ni < 8; ++ni)
                bA[ni] = *(const bf16x8*)(wt + bOff[ni] + kn);
            {
                const int kc = ((k0 + 32) >> 3) + q;
                bf16x8 af[4];
#pragma unroll
                for (int mi = 0; mi < 4; ++mi)
                    af[mi] = *(const bf16x8*)(smem + aBase[mi] + ((kc ^ s3) << 4));
#pragma unroll
                for (int mi = 0; mi < 4; ++mi)
#pragma unroll
                    for (int ni = 0; ni < 8; ++ni)
                        acc[mi][ni] = __builtin_amdgcn_mfma_f32_16x16x32_bf16(
                            af[mi], bB[ni], acc[mi][ni], 0, 0, 0);
            }
        }

        // ---- epilogue: bias + relu + residual (fp32 math) ----
        float bv[8];
#pragma unroll
        for (int ni = 0; ni < 8; ++ni)
            bv[ni] = Bias[(size_t)l * F + w * 128 + ni * 16 + r16];

        if (l == 0) {
#pragma unroll
            for (int mi = 0; mi < 4; ++mi) {
                const int rl = mi * 16 + q * 4;
#pragma unroll
                for (int ni = 0; ni < 8; ++ni) {
                    const int cl = w * 128 + ni * 16 + r16;
                    const size_t g = (size_t)(r0 + rl) * F + cl;
#pragma unroll
                    for (int j = 0; j < 4; ++j) {
                        float h = X[g + (size_t)j * F];
                        acc[mi][ni][j] = fmaxf(acc[mi][ni][j] + bv[ni], 0.f) + h;
                    }
                }
            }
        } else {
#pragma unroll
            for (int mi = 0; mi < 4; ++mi) {
                const int rl = mi * 16 + q * 4;
#pragma unroll
                for (int ni = 0; ni < 8; ++ni) {
                    const int cl = w * 128 + ni * 16 + r16;
                    const size_t g = (size_t)(r0 + rl) * F + cl;
#pragma unroll
                    for (int j = 0; j < 4; ++j) {
                        float h = (float)Hf[g + (size_t)j * F];
                        acc[mi][ni][j] = fmaxf(acc[mi][ni][j] + bv[ni], 0.f) + h;
                    }
                }
            }
        }

        // ---- LN stats: in-lane over ni, 16-lane butterfly, LDS cross-wave ----
        {
            float sS[4][4], sQ[4][4];
#pragma unroll
            for (int mi = 0; mi < 4; ++mi)
#pragma unroll
                for (int j = 0; j < 4; ++j) {
                    float s = 0.f, s2 = 0.f;
#pragma unroll
                    for (int ni = 0; ni < 8; ++ni) {
                        float y = acc[mi][ni][j];
                        s += y; s2 = fmaf(y, y, s2);
                    }
#pragma unroll
                    for (int m = 1; m < 16; m <<= 1) {
                        s  += __shfl_xor(s,  m, 64);
                        s2 += __shfl_xor(s2, m, 64);
                    }
                    sS[mi][j] = s; sQ[mi][j] = s2;
                }
            if (r16 == 0) {
#pragma unroll
                for (int mi = 0; mi < 4; ++mi)
#pragma unroll
                    for (int j = 0; j < 4; ++j) {
                        int row = mi * 16 + q * 4 + j;
                        wsS[w * 64 + row] = sS[mi][j];
                        wsQ[w * 64 + row] = sQ[mi][j];
                    }
            }
        }
        __syncthreads();
        if (tid < 64) {
            float s = 0.f, s2 = 0.f;
#pragma unroll
            for (int ww = 0; ww < 8; ++ww) {
                s  += wsS[ww * 64 + tid];
                s2 += wsQ[ww * 64 + tid];
            }
            float mean = s * (1.f / 1024.f);
            float var  = s2 * (1.f / 1024.f) - mean * mean;
            mr[tid * 2]     = mean;
            mr[tid * 2 + 1] = rsqrtf(var + LN_EPS);
        }
        __syncthreads();

        // ---- normalize; write next-h (Ab LDS + Hf fp16) or final Out ----
        if (l == L - 1) {
#pragma unroll
            for (int mi = 0; mi < 4; ++mi)
#pragma unroll
                for (int j = 0; j < 4; ++j) {
                    const int row = mi * 16 + q * 4 + j;
                    const float mean = mr[row * 2], rstd = mr[row * 2 + 1];
#pragma unroll
                    for (int ni = 0; ni < 8; ++ni) {
                        const int cl = w * 128 + ni * 16 + r16;
                        float yn = (acc[mi][ni][j] - mean) * rstd;
                        Out[(size_t)(r0 + row) * F + cl] = yn;
                    }
                }
        } else {
#pragma unroll
            for (int mi = 0; mi < 4; ++mi)
#pragma unroll
                for (int j = 0; j < 4; ++j) {
                    const int row = mi * 16 + q * 4 + j;
                    const float mean = mr[row * 2], rstd = mr[row * 2 + 1];
#pragma unroll
                    for (int ni = 0; ni < 8; ++ni) {
                        const int cl = w * 128 + ni * 16 + r16;
                        float yn = (acc[mi][ni][j] - mean) * rstd;
                        Hf[(size_t)(r0 + row) * F + cl] = (_Float16)yn;
                        int chunk = (cl >> 3) ^ (row & 7);
                        int boff  = row * 2048 + chunk * 16 + (cl & 7) * 2;
                        *(u16*)(smem + boff) = f2b(yn);
                    }
                }
        }
        __syncthreads();   // Ab fully rewritten before next layer's K-loop
    }
}

// ---------------------------------------------------------------------------
extern "C" void kernel_launch(void* const* d_in, const int* in_sizes, int n_in,
                              void* d_out, int out_size, void* d_ws, size_t ws_size,
                              hipStream_t stream) {
    const float* x    = (const float*)d_in[0];   // fp32 (N,F)
    const float* adj  = (const float*)d_in[1];   // fp32 (F,F)
    const float* W    = (const float*)d_in[2];   // fp32 (L,F,F)
    const float* bias = (const float*)d_in[3];   // fp32 (L,F)
    float* out = (float*)d_out;                  // fp32 (N,F)

    const int L = in_sizes[2] / in_sizes[1];     // 5
    const int F = in_sizes[3] / L;               // 1024
    const int N = in_sizes[0] / F;               // 16384

    const size_t ff = (size_t)F * F;

    // ws: WT all layers (L*ff bf16, 10.5 MB) + Hf fp16 residual (N*F*2,
    // 33.6 MB) = 44 MB, well under the >=71 MB proven available.
    u16* WT = (u16*)d_ws;
    _Float16* Hf = (_Float16*)((char*)d_ws + (size_t)L * ff * sizeof(u16));

    prep_weights<<<dim3(F / 64, F / 64, L), 256, 0, stream>>>(W, adj, WT, F);

    constexpr unsigned SMEM = 135680;  // 128KB Ab + 4KB stats + 0.5KB mean/rstd
    static bool attrSet = false;
    if (!attrSet) {
        (void)hipFuncSetAttribute(reinterpret_cast<const void*>(chain),
                                  hipFuncAttributeMaxDynamicSharedMemorySize,
                                  (int)SMEM);
        attrSet = true;
    }
    chain<<<N / 64, 512, SMEM, stream>>>(x, WT, bias, Hf, out, N, L);
}

// Round 2
// 967.121 us; speedup vs baseline: 1.0063x; 1.0063x over previous
//
#include <hip/hip_runtime.h>
#include <cstdint>

typedef unsigned short u16;
typedef __bf16 bf16x8 __attribute__((ext_vector_type(8)));
typedef float f32x4 __attribute__((ext_vector_type(4)));
typedef _Float16 f16x4 __attribute__((ext_vector_type(4)));

#define LN_EPS 1e-5f

__device__ __forceinline__ u16 f2b(float f) {
    union { float f; unsigned int i; } v;
    v.f = f;
    unsigned int u = v.i;
    unsigned int r = (u + 0x7FFFu + ((u >> 16) & 1u)) >> 16;  // RNE
    return (u16)r;
}

// ---------------------------------------------------------------------------
// Prep all layers: WT[z][f][k] = bf16( W[z][k][f] * adj[k][f] ), fp32 in.
// grid (F/64, F/64, L), block 256. LDS transpose for coalescing both ways.
// (unchanged, verified)
// ---------------------------------------------------------------------------
__global__ __launch_bounds__(256) void prep_weights(
    const float* __restrict__ W, const float* __restrict__ adj,
    u16* __restrict__ WT, int F)
{
    __shared__ float tile[64][65];
    const int tid = threadIdx.x;
    const size_t lofs = (size_t)blockIdx.z * F * F;
    const int kb = blockIdx.y * 64;
    const int fb = blockIdx.x * 64;
    const int c  = tid & 63;
    const int r0 = tid >> 6;

#pragma unroll
    for (int i = 0; i < 16; ++i) {
        int kl = r0 + i * 4;
        int k = kb + kl, f = fb + c;
        tile[kl][c] = W[lofs + (size_t)k * F + f] * adj[(size_t)k * F + f];
    }
    __syncthreads();
#pragma unroll
    for (int i = 0; i < 16; ++i) {
        int fl = r0 + i * 4;
        int f = fb + fl, k = kb + c;
        WT[lofs + (size_t)f * F + k] = f2b(tile[c][fl]);
    }
}

// ---------------------------------------------------------------------------
// chain: all 5 layers fused, 32 rows per block (register-pressure fix vs the
// 64-row version that spilled ~400MB of scratch to HBM).
//   - A (h, bf16) in 64KB LDS tile, XOR-swizzled chunk^(row&7): conflict-free
//     ds_read_b128 at stride 2048B.
//   - acc = 32x1024 fp32 panel in regs: f32x4[2][8] = 64 VGPRs/thread.
//   - B (WeffT) frags direct from L2 (2MB/layer, resident), dbuf prefetch,
//     barrier-free K-loop. Live set ~170 regs << 256 cap -> no spill.
//   - residual carried in a fp16 workspace laid out FRAGMENT-major: thread
//     (block,tid) owns a private 64-elem chunk it writes at layer l and reads
//     back at l+1 (8B vector ops, L2/L3-hot).
//   - LN in-block: 16-lane butterflies + small LDS cross-wave reduce.
// Block 512 thr (8 waves: wave w = cols [128w,128w+128)), grid N/32 = 512.
// ---------------------------------------------------------------------------
__global__ __launch_bounds__(512, 2) void chain(
    const float* __restrict__ X,     // (N,F) fp32 input
    const u16* __restrict__ WT,      // (L,F,K) bf16, f-major
    const float* __restrict__ Bias,  // (L,F) fp32
    _Float16* __restrict__ Hf,       // fragment-major fp16 residual ws
    float* __restrict__ Out,         // (N,F) fp32 output
    int N, int L)
{
    constexpr int F = 1024;
    constexpr int K = 1024;
    constexpr int ROWS = 32;
    extern __shared__ char smem[];
    // [0,65536): Ab [32][1024] bf16 swizzled
    float* wsS = (float*)(smem + 65536);   // [8][32] per-wave row sums
    float* wsQ = (float*)(smem + 66560);   // [8][32] per-wave row sumsq
    float* mr  = (float*)(smem + 67584);   // [32][2] mean,rstd

    const int tid  = threadIdx.x;
    const int w    = tid >> 6;        // wave 0..7 -> col slice
    const int lane = tid & 63;
    const int q    = lane >> 4;       // 0..3
    const int r16  = lane & 15;
    const int s3   = r16 & 7;         // swizzle key for A-frag reads
    const int r0   = blockIdx.x * ROWS;

    const size_t ff = (size_t)F * K;

    // ---- stage Ab from X (fp32 -> bf16, swizzled), coalesced float4 ----
    {
        const float4* Xv = (const float4*)(X + (size_t)r0 * F);
#pragma unroll 4
        for (int i = 0; i < 16; ++i) {
            int e4 = i * 512 + tid;            // 0..8191
            float4 v = Xv[e4];
            int el  = e4 * 4;
            int row = el >> 10;
            int col = el & 1023;
            int chunk = (col >> 3) ^ (row & 7);
            int boff  = row * 2048 + chunk * 16 + (col & 7) * 2;  // 8B aligned
            ushort4 pk;
            pk.x = f2b(v.x); pk.y = f2b(v.y); pk.z = f2b(v.z); pk.w = f2b(v.w);
            *(ushort4*)(smem + boff) = pk;
        }
    }
    __syncthreads();

    // per-lane constant addressing
    int aBase[2];
#pragma unroll
    for (int mi = 0; mi < 2; ++mi) aBase[mi] = (mi * 16 + r16) * 2048;
    unsigned int bOffB[8];                      // BYTE offsets into a layer's WT
#pragma unroll
    for (int ni = 0; ni < 8; ++ni)
        bOffB[ni] = (unsigned int)(((w * 128 + ni * 16 + r16) * K + q * 8) * 2);

    const size_t tb = ((size_t)blockIdx.x * 512 + tid) * 64;  // Hf chunk base

    for (int l = 0; l < L; ++l) {
        const char* wtb = (const char*)(WT + (size_t)l * ff);

        f32x4 acc[2][8];
        const f32x4 zero = {0.f, 0.f, 0.f, 0.f};
#pragma unroll
        for (int mi = 0; mi < 2; ++mi)
#pragma unroll
            for (int ni = 0; ni < 8; ++ni) acc[mi][ni] = zero;

        // ---- K-loop: barrier-free; B frags direct from L2, dbuf prefetch ----
        bf16x8 bA[8], bB[8];
#pragma unroll
        for (int ni = 0; ni < 8; ++ni)
            bA[ni] = *(const bf16x8*)(wtb + bOffB[ni]);

        for (int k0 = 0; k0 < K; k0 += 64) {
            // prefetch k0+32
#pragma unroll
            for (int ni = 0; ni < 8; ++ni)
                bB[ni] = *(const bf16x8*)(wtb + bOffB[ni] + (unsigned)(k0 + 32) * 2);
            {
                const int kc = (k0 >> 3) + q;
                bf16x8 af[2];
#pragma unroll
                for (int mi = 0; mi < 2; ++mi)
                    af[mi] = *(const bf16x8*)(smem + aBase[mi] + ((kc ^ s3) << 4));
                __builtin_amdgcn_s_setprio(1);
#pragma unroll
                for (int mi = 0; mi < 2; ++mi)
#pragma unroll
                    for (int ni = 0; ni < 8; ++ni)
                        acc[mi][ni] = __builtin_amdgcn_mfma_f32_16x16x32_bf16(
                            af[mi], bA[ni], acc[mi][ni], 0, 0, 0);
                __builtin_amdgcn_s_setprio(0);
            }
            // prefetch k0+64 (wraps to 0 on last iter; value unused)
            const unsigned kn = (unsigned)((k0 + 64) & (K - 1)) * 2;
#pragma unroll
            for (int ni = 0; ni < 8; ++ni)
                bA[ni] = *(const bf16x8*)(wtb + bOffB[ni] + kn);
            {
                const int kc = ((k0 + 32) >> 3) + q;
                bf16x8 af[2];
#pragma unroll
                for (int mi = 0; mi < 2; ++mi)
                    af[mi] = *(const bf16x8*)(smem + aBase[mi] + ((kc ^ s3) << 4));
                __builtin_amdgcn_s_setprio(1);
#pragma unroll
                for (int mi = 0; mi < 2; ++mi)
#pragma unroll
                    for (int ni = 0; ni < 8; ++ni)
                        acc[mi][ni] = __builtin_amdgcn_mfma_f32_16x16x32_bf16(
                            af[mi], bB[ni], acc[mi][ni], 0, 0, 0);
                __builtin_amdgcn_s_setprio(0);
            }
        }

        // ---- epilogue: bias + relu + residual (fp32 math) ----
        float bv[8];
#pragma unroll
        for (int ni = 0; ni < 8; ++ni)
            bv[ni] = Bias[(size_t)l * F + w * 128 + ni * 16 + r16];

        if (l == 0) {
#pragma unroll
            for (int mi = 0; mi < 2; ++mi) {
                const int rl = mi * 16 + q * 4;
#pragma unroll
                for (int ni = 0; ni < 8; ++ni) {
                    const int cl = w * 128 + ni * 16 + r16;
                    const size_t g = (size_t)(r0 + rl) * F + cl;
#pragma unroll
                    for (int j = 0; j < 4; ++j) {
                        float h = X[g + (size_t)j * F];
                        acc[mi][ni][j] = fmaxf(acc[mi][ni][j] + bv[ni], 0.f) + h;
                    }
                }
            }
        } else {
#pragma unroll
            for (int mi = 0; mi < 2; ++mi) {
#pragma unroll
                for (int ni = 0; ni < 8; ++ni) {
                    f16x4 hv = *(const f16x4*)(Hf + tb + (mi * 8 + ni) * 4);
#pragma unroll
                    for (int j = 0; j < 4; ++j) {
                        float h = (float)hv[j];
                        acc[mi][ni][j] = fmaxf(acc[mi][ni][j] + bv[ni], 0.f) + h;
                    }
                }
            }
        }

        // ---- LN stats: in-lane over ni, 16-lane butterfly, LDS cross-wave ----
        {
            float sS[2][4], sQ[2][4];
#pragma unroll
            for (int mi = 0; mi < 2; ++mi)
#pragma unroll
                for (int j = 0; j < 4; ++j) {
                    float s = 0.f, s2 = 0.f;
#pragma unroll
                    for (int ni = 0; ni < 8; ++ni) {
                        float y = acc[mi][ni][j];
                        s += y; s2 = fmaf(y, y, s2);
                    }
#pragma unroll
                    for (int m = 1; m < 16; m <<= 1) {
                        s  += __shfl_xor(s,  m, 64);
                        s2 += __shfl_xor(s2, m, 64);
                    }
                    sS[mi][j] = s; sQ[mi][j] = s2;
                }
            if (r16 == 0) {
#pragma unroll
                for (int mi = 0; mi < 2; ++mi)
#pragma unroll
                    for (int j = 0; j < 4; ++j) {
                        int row = mi * 16 + q * 4 + j;
                        wsS[w * 32 + row] = sS[mi][j];
                        wsQ[w * 32 + row] = sQ[mi][j];
                    }
            }
        }
        __syncthreads();
        if (tid < 32) {
            float s = 0.f, s2 = 0.f;
#pragma unroll
            for (int ww = 0; ww < 8; ++ww) {
                s  += wsS[ww * 32 + tid];
                s2 += wsQ[ww * 32 + tid];
            }
            float mean = s * (1.f / 1024.f);
            float var  = s2 * (1.f / 1024.f) - mean * mean;
            mr[tid * 2]     = mean;
            mr[tid * 2 + 1] = rsqrtf(var + LN_EPS);
        }
        __syncthreads();

        // per-thread mean/rstd for its 8 rows (LDS broadcast reads)
        float mean_[2][4], rstd_[2][4];
#pragma unroll
        for (int mi = 0; mi < 2; ++mi)
#pragma unroll
            for (int j = 0; j < 4; ++j) {
                int row = mi * 16 + q * 4 + j;
                mean_[mi][j] = mr[row * 2];
                rstd_[mi][j] = mr[row * 2 + 1];
            }

        // ---- normalize; write next-h (Ab LDS + Hf frag-major) or final Out ----
        if (l == L - 1) {
#pragma unroll
            for (int mi = 0; mi < 2; ++mi)
#pragma unroll
                for (int ni = 0; ni < 8; ++ni) {
                    const int cl = w * 128 + ni * 16 + r16;
#pragma unroll
                    for (int j = 0; j < 4; ++j) {
                        const int row = mi * 16 + q * 4 + j;
                        float yn = (acc[mi][ni][j] - mean_[mi][j]) * rstd_[mi][j];
                        Out[(size_t)(r0 + row) * F + cl] = yn;
                    }
                }
        } else {
#pragma unroll
            for (int mi = 0; mi < 2; ++mi)
#pragma unroll
                for (int ni = 0; ni < 8; ++ni) {
                    const int cl = w * 128 + ni * 16 + r16;
                    f16x4 hv;
#pragma unroll
                    for (int j = 0; j < 4; ++j) {
                        const int row = mi * 16 + q * 4 + j;
                        float yn = (acc[mi][ni][j] - mean_[mi][j]) * rstd_[mi][j];
                        hv[j] = (_Float16)yn;
                        int chunk = (cl >> 3) ^ (row & 7);
                        int boff  = row * 2048 + chunk * 16 + (cl & 7) * 2;
                        *(u16*)(smem + boff) = f2b(yn);
                    }
                    *(f16x4*)(Hf + tb + (mi * 8 + ni) * 4) = hv;
                }
        }
        __syncthreads();   // Ab fully rewritten before next layer's K-loop
    }
}

// ---------------------------------------------------------------------------
extern "C" void kernel_launch(void* const* d_in, const int* in_sizes, int n_in,
                              void* d_out, int out_size, void* d_ws, size_t ws_size,
                              hipStream_t stream) {
    const float* x    = (const float*)d_in[0];   // fp32 (N,F)
    const float* adj  = (const float*)d_in[1];   // fp32 (F,F)
    const float* W    = (const float*)d_in[2];   // fp32 (L,F,F)
    const float* bias = (const float*)d_in[3];   // fp32 (L,F)
    float* out = (float*)d_out;                  // fp32 (N,F)

    const int L = in_sizes[2] / in_sizes[1];     // 5
    const int F = in_sizes[3] / L;               // 1024
    const int N = in_sizes[0] / F;               // 16384

    const size_t ff = (size_t)F * F;

    // ws: WT all layers (L*ff bf16, 10.5 MB) + Hf fp16 residual frag-major
    // (N*F*2 = 33.6 MB) = 44 MB.
    u16* WT = (u16*)d_ws;
    _Float16* Hf = (_Float16*)((char*)d_ws + (size_t)L * ff * sizeof(u16));

    prep_weights<<<dim3(F / 64, F / 64, L), 256, 0, stream>>>(W, adj, WT, F);

    constexpr unsigned SMEM = 67840;  // 64KB Ab + 2KB stats + 256B mean/rstd
    static bool attrSet = false;
    if (!attrSet) {
        (void)hipFuncSetAttribute(reinterpret_cast<const void*>(chain),
                                  hipFuncAttributeMaxDynamicSharedMemorySize,
                                  (int)SMEM);
        attrSet = true;
    }
    chain<<<N / 32, 512, SMEM, stream>>>(x, WT, bias, Hf, out, N, L);
}

// Round 3
// 855.882 us; speedup vs baseline: 1.1371x; 1.1300x over previous
//
#include <hip/hip_runtime.h>
#include <cstdint>

typedef unsigned short u16;
typedef __bf16 bf16x8 __attribute__((ext_vector_type(8)));
typedef float f32x4 __attribute__((ext_vector_type(4)));
typedef _Float16 f16x8 __attribute__((ext_vector_type(8)));

#define LN_EPS 1e-5f

__device__ __forceinline__ u16 f2b(float f) {
    union { float f; unsigned int i; } v;
    v.f = f;
    unsigned int u = v.i;
    unsigned int r = (u + 0x7FFFu + ((u >> 16) & 1u)) >> 16;  // RNE
    return (u16)r;
}

__device__ __forceinline__ void async_copy16(const u16* g, u16* l) {
    __builtin_amdgcn_global_load_lds(
        (const __attribute__((address_space(1))) u16*)g,
        (__attribute__((address_space(3))) u16*)l,
        16, 0, 0);
}

// ---------------------------------------------------------------------------
// Prep all layers: WT[z][f][k] = bf16( W[z][k][f] * adj[k][f] ), fp32 in.
// (unchanged, verified)
// ---------------------------------------------------------------------------
__global__ __launch_bounds__(256) void prep_weights(
    const float* __restrict__ W, const float* __restrict__ adj,
    u16* __restrict__ WT, int F)
{
    __shared__ float tile[64][65];
    const int tid = threadIdx.x;
    const size_t lofs = (size_t)blockIdx.z * F * F;
    const int kb = blockIdx.y * 64;
    const int fb = blockIdx.x * 64;
    const int c  = tid & 63;
    const int r0 = tid >> 6;

#pragma unroll
    for (int i = 0; i < 16; ++i) {
        int kl = r0 + i * 4;
        int k = kb + kl, f = fb + c;
        tile[kl][c] = W[lofs + (size_t)k * F + f] * adj[(size_t)k * F + f];
    }
    __syncthreads();
#pragma unroll
    for (int i = 0; i < 16; ++i) {
        int fl = r0 + i * 4;
        int f = fb + fl, k = kb + c;
        WT[lofs + (size_t)f * F + k] = f2b(tile[c][fl]);
    }
}

// ---------------------------------------------------------------------------
// chain v3: all 5 layers fused, 32 rows/block. K-loop rebuilt around
// global_load_lds-staged B (the proven m97 mechanism) instead of direct
// per-lane global loads (R2: 13k cyc/iter, latency-bound at 2 waves/SIMD).
//   - A (h, bf16) resident in 64KB swizzled LDS across all layers.
//   - B: per BK=32 step, block stages the 64KB slab [1024 cols][32 k] via
//     8 async 16B issues/thread; frags via ds_read_b128.
//   - pipeline: read frags -> barrier -> issue NEXT stage -> MFMA, so the
//     ~1170cyc L2-BW stage overlaps current step's compute (regs = 2nd buf).
//   - acc 64 AGPR; VGPR ~100 -> no spill.
//   - LN + fp16 residual (wave-contiguous layout, 1KB bursts) as before.
// LDS: 64KB A + 64KB B (epilogue stats aliased into B) = 128KB, 1 block/CU.
// ---------------------------------------------------------------------------
__global__ __launch_bounds__(512, 2) void chain(
    const float* __restrict__ X,     // (N,F) fp32 input
    const u16* __restrict__ WT,      // (L,F,K) bf16, f-major
    const float* __restrict__ Bias,  // (L,F) fp32
    _Float16* __restrict__ Hf,       // fp16 residual ws, wave-contiguous
    float* __restrict__ Out,         // (N,F) fp32 output
    int N, int L)
{
    constexpr int F = 1024;
    constexpr int K = 1024;
    constexpr int ROWS = 32;
    extern __shared__ char smem[];
    u16*   Bl  = (u16*)(smem + 65536);     // [1024][32] bf16 B slab (64KB)
    float* wsS = (float*)(smem + 65536);   // aliased: epilogue-only
    float* wsQ = (float*)(smem + 66560);
    float* mr  = (float*)(smem + 67584);   // [32][2] mean,rstd

    const int tid  = threadIdx.x;
    const int w    = tid >> 6;        // wave 0..7 -> col slice
    const int lane = tid & 63;
    const int q    = lane >> 4;       // 0..3
    const int r16  = lane & 15;
    const int s3   = r16 & 7;         // A-swizzle key
    const int r0   = blockIdx.x * ROWS;

    const size_t ff = (size_t)F * K;

    // ---- stage A from X (fp32 -> bf16, swizzled), coalesced float4 ----
    {
        const float4* Xv = (const float4*)(X + (size_t)r0 * F);
#pragma unroll 4
        for (int i = 0; i < 16; ++i) {
            int e4 = i * 512 + tid;            // 0..8191
            float4 v = Xv[e4];
            int el  = e4 * 4;
            int row = el >> 10;
            int col = el & 1023;
            int chunk = (col >> 3) ^ (row & 7);
            int boff  = row * 2048 + chunk * 16 + (col & 7) * 2;
            ushort4 pk;
            pk.x = f2b(v.x); pk.y = f2b(v.y); pk.z = f2b(v.z); pk.w = f2b(v.w);
            *(ushort4*)(smem + boff) = pk;
        }
    }
    __syncthreads();

    int aBase[2];
#pragma unroll
    for (int mi = 0; mi < 2; ++mi) aBase[mi] = (mi * 16 + r16) * 2048;

    // B staging geometry: issue i of wave w covers 16 cols x 32 k (1KB);
    // lane l -> col colBase + (l>>2), k-part (l&3)*8. LDS linear: col*32+8*l.
    const int lcol = lane >> 2;
    const int lkof = (lane & 3) * 8;

    // Hf: [block][wave][8 j][64 lanes][8 elems]
    const size_t hb = (size_t)blockIdx.x * (512 * 64) + (size_t)w * 4096
                    + (size_t)lane * 8;

    for (int l = 0; l < L; ++l) {
        const u16* wt = WT + (size_t)l * ff;

        f32x4 acc[2][8];
        const f32x4 zero = {0.f, 0.f, 0.f, 0.f};
#pragma unroll
        for (int mi = 0; mi < 2; ++mi)
#pragma unroll
            for (int ni = 0; ni < 8; ++ni) acc[mi][ni] = zero;

        // prologue stage: k0 = 0
#pragma unroll
        for (int i = 0; i < 8; ++i) {
            const int colBase = (w * 8 + i) * 16;
            async_copy16(wt + (size_t)(colBase + lcol) * K + lkof,
                         Bl + colBase * 32);
        }

        for (int k0 = 0; k0 < K; k0 += 32) {
            __syncthreads();               // staging(k0) drained + landed

            // frags -> regs
            const int kc = (k0 >> 3) + q;
            bf16x8 af[2];
#pragma unroll
            for (int mi = 0; mi < 2; ++mi)
                af[mi] = *(const bf16x8*)(smem + aBase[mi] + ((kc ^ s3) << 4));
            bf16x8 bfr[8];
#pragma unroll
            for (int ni = 0; ni < 8; ++ni)
                bfr[ni] = *(const bf16x8*)(Bl + (w * 128 + ni * 16 + r16) * 32
                                              + q * 8);

            __syncthreads();               // all waves done reading Bl

            if (k0 + 32 < K) {             // issue next stage (overlaps MFMA)
#pragma unroll
                for (int i = 0; i < 8; ++i) {
                    const int colBase = (w * 8 + i) * 16;
                    async_copy16(wt + (size_t)(colBase + lcol) * K
                                    + (k0 + 32) + lkof,
                                 Bl + colBase * 32);
                }
            }

#pragma unroll
            for (int mi = 0; mi < 2; ++mi)
#pragma unroll
                for (int ni = 0; ni < 8; ++ni)
                    acc[mi][ni] = __builtin_amdgcn_mfma_f32_16x16x32_bf16(
                        af[mi], bfr[ni], acc[mi][ni], 0, 0, 0);
        }

        // ---- epilogue: bias + relu + residual (fp32 math) ----
        float bv[8];
#pragma unroll
        for (int ni = 0; ni < 8; ++ni)
            bv[ni] = Bias[(size_t)l * F + w * 128 + ni * 16 + r16];

        if (l == 0) {
#pragma unroll
            for (int mi = 0; mi < 2; ++mi) {
                const int rl = mi * 16 + q * 4;
#pragma unroll
                for (int ni = 0; ni < 8; ++ni) {
                    const int cl = w * 128 + ni * 16 + r16;
                    const size_t g = (size_t)(r0 + rl) * F + cl;
#pragma unroll
                    for (int j = 0; j < 4; ++j) {
                        float h = X[g + (size_t)j * F];
                        acc[mi][ni][j] = fmaxf(acc[mi][ni][j] + bv[ni], 0.f) + h;
                    }
                }
            }
        } else {
#pragma unroll
            for (int j = 0; j < 8; ++j) {
                f16x8 v = *(const f16x8*)(Hf + hb + j * 512);
#pragma unroll
                for (int half = 0; half < 2; ++half) {
                    const int c  = j * 2 + half;
                    const int mi = c >> 3, ni = c & 7;
#pragma unroll
                    for (int jj = 0; jj < 4; ++jj) {
                        float h = (float)v[half * 4 + jj];
                        acc[mi][ni][jj] =
                            fmaxf(acc[mi][ni][jj] + bv[ni], 0.f) + h;
                    }
                }
            }
        }

        // ---- LN stats ----
        {
            float sS[2][4], sQ[2][4];
#pragma unroll
            for (int mi = 0; mi < 2; ++mi)
#pragma unroll
                for (int j = 0; j < 4; ++j) {
                    float s = 0.f, s2 = 0.f;
#pragma unroll
                    for (int ni = 0; ni < 8; ++ni) {
                        float y = acc[mi][ni][j];
                        s += y; s2 = fmaf(y, y, s2);
                    }
#pragma unroll
                    for (int m = 1; m < 16; m <<= 1) {
                        s  += __shfl_xor(s,  m, 64);
                        s2 += __shfl_xor(s2, m, 64);
                    }
                    sS[mi][j] = s; sQ[mi][j] = s2;
                }
            if (r16 == 0) {
#pragma unroll
                for (int mi = 0; mi < 2; ++mi)
#pragma unroll
                    for (int j = 0; j < 4; ++j) {
                        int row = mi * 16 + q * 4 + j;
                        wsS[w * 32 + row] = sS[mi][j];
                        wsQ[w * 32 + row] = sQ[mi][j];
                    }
            }
        }
        __syncthreads();
        if (tid < 32) {
            float s = 0.f, s2 = 0.f;
#pragma unroll
            for (int ww = 0; ww < 8; ++ww) {
                s  += wsS[ww * 32 + tid];
                s2 += wsQ[ww * 32 + tid];
            }
            float mean = s * (1.f / 1024.f);
            float var  = s2 * (1.f / 1024.f) - mean * mean;
            mr[tid * 2]     = mean;
            mr[tid * 2 + 1] = rsqrtf(var + LN_EPS);
        }
        __syncthreads();

        float mean_[2][4], rstd_[2][4];
#pragma unroll
        for (int mi = 0; mi < 2; ++mi)
#pragma unroll
            for (int j = 0; j < 4; ++j) {
                int row = mi * 16 + q * 4 + j;
                mean_[mi][j] = mr[row * 2];
                rstd_[mi][j] = mr[row * 2 + 1];
            }

        // ---- normalize; write next-h (A LDS + Hf) or final Out ----
        if (l == L - 1) {
#pragma unroll
            for (int mi = 0; mi < 2; ++mi)
#pragma unroll
                for (int ni = 0; ni < 8; ++ni) {
                    const int cl = w * 128 + ni * 16 + r16;
#pragma unroll
                    for (int j = 0; j < 4; ++j) {
                        const int row = mi * 16 + q * 4 + j;
                        float yn = (acc[mi][ni][j] - mean_[mi][j]) * rstd_[mi][j];
                        Out[(size_t)(r0 + row) * F + cl] = yn;
                    }
                }
        } else {
            _Float16 hbuf[64];
#pragma unroll
            for (int mi = 0; mi < 2; ++mi)
#pragma unroll
                for (int ni = 0; ni < 8; ++ni) {
                    const int cl = w * 128 + ni * 16 + r16;
#pragma unroll
                    for (int j = 0; j < 4; ++j) {
                        const int row = mi * 16 + q * 4 + j;
                        float yn = (acc[mi][ni][j] - mean_[mi][j]) * rstd_[mi][j];
                        hbuf[(mi * 8 + ni) * 4 + j] = (_Float16)yn;
                        int chunk = (cl >> 3) ^ (row & 7);
                        int boff  = row * 2048 + chunk * 16 + (cl & 7) * 2;
                        *(u16*)(smem + boff) = f2b(yn);
                    }
                }
#pragma unroll
            for (int j = 0; j < 8; ++j)
                *(f16x8*)(Hf + hb + j * 512) = *(const f16x8*)(hbuf + j * 8);
        }
        __syncthreads();   // A rewritten + stats consumed before next staging
    }
}

// ---------------------------------------------------------------------------
extern "C" void kernel_launch(void* const* d_in, const int* in_sizes, int n_in,
                              void* d_out, int out_size, void* d_ws, size_t ws_size,
                              hipStream_t stream) {
    const float* x    = (const float*)d_in[0];   // fp32 (N,F)
    const float* adj  = (const float*)d_in[1];   // fp32 (F,F)
    const float* W    = (const float*)d_in[2];   // fp32 (L,F,F)
    const float* bias = (const float*)d_in[3];   // fp32 (L,F)
    float* out = (float*)d_out;                  // fp32 (N,F)

    const int L = in_sizes[2] / in_sizes[1];     // 5
    const int F = in_sizes[3] / L;               // 1024
    const int N = in_sizes[0] / F;               // 16384

    const size_t ff = (size_t)F * F;

    // ws: WT (L*ff bf16, 10.5 MB) + Hf fp16 residual (N*F*2 = 33.6 MB)
    u16* WT = (u16*)d_ws;
    _Float16* Hf = (_Float16*)((char*)d_ws + (size_t)L * ff * sizeof(u16));

    prep_weights<<<dim3(F / 64, F / 64, L), 256, 0, stream>>>(W, adj, WT, F);

    constexpr unsigned SMEM = 131072;  // 64KB A + 64KB B (stats aliased)
    static bool attrSet = false;
    if (!attrSet) {
        (void)hipFuncSetAttribute(reinterpret_cast<const void*>(chain),
                                  hipFuncAttributeMaxDynamicSharedMemorySize,
                                  (int)SMEM);
        attrSet = true;
    }
    chain<<<N / 32, 512, SMEM, stream>>>(x, WT, bias, Hf, out, N, L);
}

// Round 4
// 736.926 us; speedup vs baseline: 1.3206x; 1.1614x over previous
//
#include <hip/hip_runtime.h>
#include <cstdint>

typedef unsigned short u16;
typedef __bf16 bf16x8 __attribute__((ext_vector_type(8)));
typedef float f32x4 __attribute__((ext_vector_type(4)));
typedef _Float16 f16x8 __attribute__((ext_vector_type(8)));

#define LN_EPS 1e-5f

__device__ __forceinline__ u16 f2b(float f) {
    union { float f; unsigned int i; } v;
    v.f = f;
    unsigned int u = v.i;
    unsigned int r = (u + 0x7FFFu + ((u >> 16) & 1u)) >> 16;  // RNE
    return (u16)r;
}

__device__ __forceinline__ void async_copy16(const u16* g, u16* l) {
    __builtin_amdgcn_global_load_lds(
        (const __attribute__((address_space(1))) u16*)g,
        (__attribute__((address_space(3))) u16*)l,
        16, 0, 0);
}

// ---------------------------------------------------------------------------
// Prep all layers: WT[z][f][k] = bf16( W[z][k][f] * adj[k][f] ), fp32 in.
// (unchanged, verified)
// ---------------------------------------------------------------------------
__global__ __launch_bounds__(256) void prep_weights(
    const float* __restrict__ W, const float* __restrict__ adj,
    u16* __restrict__ WT, int F)
{
    __shared__ float tile[64][65];
    const int tid = threadIdx.x;
    const size_t lofs = (size_t)blockIdx.z * F * F;
    const int kb = blockIdx.y * 64;
    const int fb = blockIdx.x * 64;
    const int c  = tid & 63;
    const int r0 = tid >> 6;

#pragma unroll
    for (int i = 0; i < 16; ++i) {
        int kl = r0 + i * 4;
        int k = kb + kl, f = fb + c;
        tile[kl][c] = W[lofs + (size_t)k * F + f] * adj[(size_t)k * F + f];
    }
    __syncthreads();
#pragma unroll
    for (int i = 0; i < 16; ++i) {
        int fl = r0 + i * 4;
        int f = fb + fl, k = kb + c;
        WT[lofs + (size_t)f * F + k] = f2b(tile[c][fl]);
    }
}

// ---------------------------------------------------------------------------
// chain v4: barrier-free K-loop. Each wave owns 128 cols split in two halves
// (buf0 = cols 0..511, buf1 = 512..1023 of the block's B working set) and
// stages ONLY its own 4KB slice per phase -> no cross-wave dependency -> no
// barriers, just per-wave counted vmcnt(4) (stage p+1 in flight while stage p
// is consumed). R3's two full-drain __syncthreads per K-step exposed the
// whole L2/L3 stage latency serially (MfmaUtil 8.8%, 83% stall).
//   - A (h, bf16) resident in 64KB swizzled LDS across all layers.
//   - acc = 32 rows x 1024 cols fp32 in regs (64 AGPR).
//   - Hf fp16 residual + Out use nontemporal ld/st so the streams stop
//     evicting the 2MB WT slab from the 4MB XCD L2.
// LDS: 64KB A + 32KB buf0 + 32KB buf1 = 128KB (stats aliased into buf0,
// only touched after a post-K-loop barrier). 1 block/CU, 2 waves/SIMD.
// ---------------------------------------------------------------------------
__global__ __launch_bounds__(512, 2) void chain(
    const float* __restrict__ X,     // (N,F) fp32 input
    const u16* __restrict__ WT,      // (L,F,K) bf16, f-major
    const float* __restrict__ Bias,  // (L,F) fp32
    _Float16* __restrict__ Hf,       // fp16 residual ws, wave-contiguous
    float* __restrict__ Out,         // (N,F) fp32 output
    int N, int L)
{
    constexpr int F = 1024;
    constexpr int K = 1024;
    constexpr int ROWS = 32;
    extern __shared__ char smem[];
    // [0,65536): A tile [32][1024] bf16, swizzled
    // [65536,98304): buf0 (cols 0..511 x 32k)   [98304,131072): buf1
    float* wsS = (float*)(smem + 65536);   // aliased into buf0 (epilogue only)
    float* wsQ = (float*)(smem + 66560);
    float* mr  = (float*)(smem + 67584);   // [32][2] mean,rstd

    const int tid  = threadIdx.x;
    const int w    = tid >> 6;        // wave 0..7
    const int lane = tid & 63;
    const int q    = lane >> 4;       // 0..3
    const int r16  = lane & 15;
    const int s3   = r16 & 7;         // A-swizzle key
    const int r0   = blockIdx.x * ROWS;

    const size_t ff = (size_t)F * K;

    // ---- stage A from X (fp32 -> bf16, swizzled), coalesced float4 ----
    {
        const float4* Xv = (const float4*)(X + (size_t)r0 * F);
#pragma unroll 4
        for (int i = 0; i < 16; ++i) {
            int e4 = i * 512 + tid;            // 0..8191
            float4 v = Xv[e4];
            int el  = e4 * 4;
            int row = el >> 10;
            int col = el & 1023;
            int chunk = (col >> 3) ^ (row & 7);
            int boff  = row * 2048 + chunk * 16 + (col & 7) * 2;
            ushort4 pk;
            pk.x = f2b(v.x); pk.y = f2b(v.y); pk.z = f2b(v.z); pk.w = f2b(v.w);
            *(ushort4*)(smem + boff) = pk;
        }
    }
    __syncthreads();

    const int aB0 = (0 * 16 + r16) * 2048;
    const int aB1 = (1 * 16 + r16) * 2048;

    // staging geometry: per issue, 64 lanes x 16B = 16 cols x 32 k (1KB).
    const int lcol = lane >> 2;         // 0..15
    const int lkof = (lane & 3) * 8;    // 0,8,16,24

    u16* bufW0 = (u16*)(smem + 65536) + w * 2048;   // wave slice in buf0
    u16* bufW1 = (u16*)(smem + 98304) + w * 2048;
    const char* rb0 = smem + 65536 + w * 4096 + r16 * 64 + q * 16;
    const char* rb1 = smem + 98304 + w * 4096 + r16 * 64 + q * 16;

    // Hf: [block][wave][8 j][64 lanes][8 elems]
    const size_t hb = (size_t)blockIdx.x * (512 * 64) + (size_t)w * 4096
                    + (size_t)lane * 8;

    for (int l = 0; l < L; ++l) {
        const u16* wt = WT + (size_t)l * ff;
        // per-wave source col bases (elements): nh0 and nh1
        const u16* src0 = wt + (size_t)(w * 64 + lcol) * K + lkof;
        const u16* src1 = wt + (size_t)(512 + w * 64 + lcol) * K + lkof;

        f32x4 acc[2][8];
        const f32x4 zero = {0.f, 0.f, 0.f, 0.f};
#pragma unroll
        for (int mi = 0; mi < 2; ++mi)
#pragma unroll
            for (int ni = 0; ni < 8; ++ni) acc[mi][ni] = zero;

        // prologue: stage (nh0, k0=0) -> buf0
#pragma unroll
        for (int i = 0; i < 4; ++i)
            async_copy16(src0 + (size_t)i * 16 * K, bufW0 + i * 512);

        for (int kp = 0; kp < 32; ++kp) {
            const int k0 = kp * 32;

            // ---- even phase: consume buf0(nh0,k0), stage buf1(nh1,k0) ----
            // buf1 was read last odd phase: ensure those ds_reads sampled.
            asm volatile("s_waitcnt lgkmcnt(0)" ::: "memory");
#pragma unroll
            for (int i = 0; i < 4; ++i)
                async_copy16(src1 + (size_t)i * 16 * K + k0, bufW1 + i * 512);
            asm volatile("s_waitcnt vmcnt(4)" ::: "memory");  // buf0 landed

            const int kc = (k0 >> 3) + q;
            bf16x8 af0 = *(const bf16x8*)(smem + aB0 + ((kc ^ s3) << 4));
            bf16x8 af1 = *(const bf16x8*)(smem + aB1 + ((kc ^ s3) << 4));
            bf16x8 b0[4];
#pragma unroll
            for (int nl = 0; nl < 4; ++nl)
                b0[nl] = *(const bf16x8*)(rb0 + nl * 1024);
            __builtin_amdgcn_s_setprio(1);
#pragma unroll
            for (int nl = 0; nl < 4; ++nl) {
                acc[0][nl] = __builtin_amdgcn_mfma_f32_16x16x32_bf16(
                    af0, b0[nl], acc[0][nl], 0, 0, 0);
                acc[1][nl] = __builtin_amdgcn_mfma_f32_16x16x32_bf16(
                    af1, b0[nl], acc[1][nl], 0, 0, 0);
            }
            __builtin_amdgcn_s_setprio(0);

            // ---- odd phase: consume buf1(nh1,k0), stage buf0(nh0,k0+32) ----
            asm volatile("s_waitcnt lgkmcnt(0)" ::: "memory");  // b0 sampled
            if (kp < 31) {
#pragma unroll
                for (int i = 0; i < 4; ++i)
                    async_copy16(src0 + (size_t)i * 16 * K + (k0 + 32),
                                 bufW0 + i * 512);
                asm volatile("s_waitcnt vmcnt(4)" ::: "memory");  // buf1 landed
            } else {
                asm volatile("s_waitcnt vmcnt(0)" ::: "memory");
            }
            bf16x8 b1[4];
#pragma unroll
            for (int nl = 0; nl < 4; ++nl)
                b1[nl] = *(const bf16x8*)(rb1 + nl * 1024);
            __builtin_amdgcn_s_setprio(1);
#pragma unroll
            for (int nl = 0; nl < 4; ++nl) {
                acc[0][4 + nl] = __builtin_amdgcn_mfma_f32_16x16x32_bf16(
                    af0, b1[nl], acc[0][4 + nl], 0, 0, 0);
                acc[1][4 + nl] = __builtin_amdgcn_mfma_f32_16x16x32_bf16(
                    af1, b1[nl], acc[1][4 + nl], 0, 0, 0);
            }
            __builtin_amdgcn_s_setprio(0);
        }

        // ---- epilogue: bias + relu + residual (fp32 math) ----
        // col(ni) = (ni>>2)*512 + w*64 + (ni&3)*16 + r16
        float bv[8];
#pragma unroll
        for (int ni = 0; ni < 8; ++ni)
            bv[ni] = Bias[(size_t)l * F + (ni >> 2) * 512 + w * 64
                          + (ni & 3) * 16 + r16];

        if (l == 0) {
#pragma unroll
            for (int mi = 0; mi < 2; ++mi) {
                const int rl = mi * 16 + q * 4;
#pragma unroll
                for (int ni = 0; ni < 8; ++ni) {
                    const int cl = (ni >> 2) * 512 + w * 64 + (ni & 3) * 16 + r16;
                    const size_t g = (size_t)(r0 + rl) * F + cl;
#pragma unroll
                    for (int j = 0; j < 4; ++j) {
                        float h = X[g + (size_t)j * F];
                        acc[mi][ni][j] = fmaxf(acc[mi][ni][j] + bv[ni], 0.f) + h;
                    }
                }
            }
        } else {
#pragma unroll
            for (int j = 0; j < 8; ++j) {
                f16x8 v = __builtin_nontemporal_load(
                    (const f16x8*)(Hf + hb + j * 512));
#pragma unroll
                for (int half = 0; half < 2; ++half) {
                    const int c  = j * 2 + half;
                    const int mi = c >> 3, ni = c & 7;
#pragma unroll
                    for (int jj = 0; jj < 4; ++jj) {
                        float h = (float)v[half * 4 + jj];
                        acc[mi][ni][jj] =
                            fmaxf(acc[mi][ni][jj] + bv[ni], 0.f) + h;
                    }
                }
            }
        }

        // ---- LN stats ----
        float sS[2][4], sQ[2][4];
#pragma unroll
        for (int mi = 0; mi < 2; ++mi)
#pragma unroll
            for (int j = 0; j < 4; ++j) {
                float s = 0.f, s2 = 0.f;
#pragma unroll
                for (int ni = 0; ni < 8; ++ni) {
                    float y = acc[mi][ni][j];
                    s += y; s2 = fmaf(y, y, s2);
                }
#pragma unroll
                for (int m = 1; m < 16; m <<= 1) {
                    s  += __shfl_xor(s,  m, 64);
                    s2 += __shfl_xor(s2, m, 64);
                }
                sS[mi][j] = s; sQ[mi][j] = s2;
            }

        __syncthreads();   // all waves done with K-loop LDS before stats alias
        if (r16 == 0) {
#pragma unroll
            for (int mi = 0; mi < 2; ++mi)
#pragma unroll
                for (int j = 0; j < 4; ++j) {
                    int row = mi * 16 + q * 4 + j;
                    wsS[w * 32 + row] = sS[mi][j];
                    wsQ[w * 32 + row] = sQ[mi][j];
                }
        }
        __syncthreads();
        if (tid < 32) {
            float s = 0.f, s2 = 0.f;
#pragma unroll
            for (int ww = 0; ww < 8; ++ww) {
                s  += wsS[ww * 32 + tid];
                s2 += wsQ[ww * 32 + tid];
            }
            float mean = s * (1.f / 1024.f);
            float var  = s2 * (1.f / 1024.f) - mean * mean;
            mr[tid * 2]     = mean;
            mr[tid * 2 + 1] = rsqrtf(var + LN_EPS);
        }
        __syncthreads();

        float mean_[2][4], rstd_[2][4];
#pragma unroll
        for (int mi = 0; mi < 2; ++mi)
#pragma unroll
            for (int j = 0; j < 4; ++j) {
                int row = mi * 16 + q * 4 + j;
                mean_[mi][j] = mr[row * 2];
                rstd_[mi][j] = mr[row * 2 + 1];
            }

        // ---- normalize; write next-h (A LDS + Hf nt) or final Out (nt) ----
        if (l == L - 1) {
#pragma unroll
            for (int mi = 0; mi < 2; ++mi)
#pragma unroll
                for (int ni = 0; ni < 8; ++ni) {
                    const int cl = (ni >> 2) * 512 + w * 64 + (ni & 3) * 16 + r16;
#pragma unroll
                    for (int j = 0; j < 4; ++j) {
                        const int row = mi * 16 + q * 4 + j;
                        float yn = (acc[mi][ni][j] - mean_[mi][j]) * rstd_[mi][j];
                        __builtin_nontemporal_store(
                            yn, Out + (size_t)(r0 + row) * F + cl);
                    }
                }
        } else {
            _Float16 hbuf[64];
#pragma unroll
            for (int mi = 0; mi < 2; ++mi)
#pragma unroll
                for (int ni = 0; ni < 8; ++ni) {
                    const int cl = (ni >> 2) * 512 + w * 64 + (ni & 3) * 16 + r16;
#pragma unroll
                    for (int j = 0; j < 4; ++j) {
                        const int row = mi * 16 + q * 4 + j;
                        float yn = (acc[mi][ni][j] - mean_[mi][j]) * rstd_[mi][j];
                        hbuf[(mi * 8 + ni) * 4 + j] = (_Float16)yn;
                        int chunk = (cl >> 3) ^ (row & 7);
                        int boff  = row * 2048 + chunk * 16 + (cl & 7) * 2;
                        *(u16*)(smem + boff) = f2b(yn);
                    }
                }
#pragma unroll
            for (int j = 0; j < 8; ++j)
                __builtin_nontemporal_store(
                    *(const f16x8*)(hbuf + j * 8), (f16x8*)(Hf + hb + j * 512));
        }
        __syncthreads();   // A rewritten + mr consumed before next staging
    }
}

// ---------------------------------------------------------------------------
extern "C" void kernel_launch(void* const* d_in, const int* in_sizes, int n_in,
                              void* d_out, int out_size, void* d_ws, size_t ws_size,
                              hipStream_t stream) {
    const float* x    = (const float*)d_in[0];   // fp32 (N,F)
    const float* adj  = (const float*)d_in[1];   // fp32 (F,F)
    const float* W    = (const float*)d_in[2];   // fp32 (L,F,F)
    const float* bias = (const float*)d_in[3];   // fp32 (L,F)
    float* out = (float*)d_out;                  // fp32 (N,F)

    const int L = in_sizes[2] / in_sizes[1];     // 5
    const int F = in_sizes[3] / L;               // 1024
    const int N = in_sizes[0] / F;               // 16384

    const size_t ff = (size_t)F * F;

    // ws: WT (L*ff bf16, 10.5 MB) + Hf fp16 residual (N*F*2 = 33.6 MB)
    u16* WT = (u16*)d_ws;
    _Float16* Hf = (_Float16*)((char*)d_ws + (size_t)L * ff * sizeof(u16));

    prep_weights<<<dim3(F / 64, F / 64, L), 256, 0, stream>>>(W, adj, WT, F);

    constexpr unsigned SMEM = 131072;  // 64KB A + 2x32KB B dbuf
    static bool attrSet = false;
    if (!attrSet) {
        (void)hipFuncSetAttribute(reinterpret_cast<const void*>(chain),
                                  hipFuncAttributeMaxDynamicSharedMemorySize,
                                  (int)SMEM);
        attrSet = true;
    }
    chain<<<N / 32, 512, SMEM, stream>>>(x, WT, bias, Hf, out, N, L);
}

// Round 5
// 656.608 us; speedup vs baseline: 1.4822x; 1.1223x over previous
//
#include <hip/hip_runtime.h>
#include <cstdint>

typedef unsigned short u16;
typedef __bf16 bf16x8 __attribute__((ext_vector_type(8)));
typedef float f32x4 __attribute__((ext_vector_type(4)));
typedef _Float16 f16x8 __attribute__((ext_vector_type(8)));

#define LN_EPS 1e-5f

__device__ __forceinline__ u16 f2b(float f) {
    union { float f; unsigned int i; } v;
    v.f = f;
    unsigned int u = v.i;
    unsigned int r = (u + 0x7FFFu + ((u >> 16) & 1u)) >> 16;  // RNE
    return (u16)r;
}

// ---------------------------------------------------------------------------
// prep_weights v2: emit WT in MFMA-FRAGMENT-PACKED layout.
//   group g = kp*64 + cg   (kp = k/32, cg = col/16; 2048 groups/layer)
//   within group: lane = q*16 + r16  (col = cg*16+r16, k = kp*32+q*8+j)
//   elem addr = (g*64 + lane)*8 + j
// A wave's B-fragment load for (cg,kp) is then ONE contiguous 1KB burst
// (lane l -> 16B at base + l*16). This is what makes register-direct B
// loads coalesced (R2's direct loads gathered 16 lines at 2KB stride).
// grid (F/64 cols, F/64 ks, L), block 256.
// ---------------------------------------------------------------------------
__global__ __launch_bounds__(256) void prep_weights(
    const float* __restrict__ W, const float* __restrict__ adj,
    u16* __restrict__ WTp, int F)
{
    __shared__ float tile[64][65];
    const int tid = threadIdx.x;
    const size_t lofs = (size_t)blockIdx.z * F * F;
    const int kb = blockIdx.y * 64;
    const int fb = blockIdx.x * 64;
    const int c  = tid & 63;
    const int r0t = tid >> 6;

#pragma unroll
    for (int i = 0; i < 16; ++i) {
        int kl = r0t + i * 4;
        int k = kb + kl, f = fb + c;
        tile[kl][c] = W[lofs + (size_t)k * F + f] * adj[(size_t)k * F + f];
    }
    __syncthreads();

#pragma unroll
    for (int c2 = 0; c2 < 2; ++c2) {
        const int cid   = c2 * 256 + tid;      // 0..511 16B-chunks
        const int lane_ = cid & 63;
        const int cgl   = (cid >> 6) & 3;      // local colgroup 0..3
        const int kp2   = cid >> 8;            // local kp 0..1
        const int fl    = cgl * 16 + (lane_ & 15);
        const int klb   = kp2 * 32 + (lane_ >> 4) * 8;
        const size_t g  = (size_t)((kb >> 5) + kp2) * 64 + (fb >> 4) + cgl;
        u16* dst = WTp + lofs + (g * 64 + lane_) * 8;
        ushort4 lo, hi;
        lo.x = f2b(tile[klb + 0][fl]); lo.y = f2b(tile[klb + 1][fl]);
        lo.z = f2b(tile[klb + 2][fl]); lo.w = f2b(tile[klb + 3][fl]);
        hi.x = f2b(tile[klb + 4][fl]); hi.y = f2b(tile[klb + 5][fl]);
        hi.z = f2b(tile[klb + 6][fl]); hi.w = f2b(tile[klb + 7][fl]);
        ((ushort4*)dst)[0] = lo;
        ((ushort4*)dst)[1] = hi;
    }
}

// ---------------------------------------------------------------------------
// chain v5: all 5 layers fused, 32 rows/block, NO B-LDS.
//   - B frags loaded register-direct from fragment-packed WT: each load is a
//     coalesced 1KB burst from the L2-resident 2MB slab. Rolling half-buffer
//     (b0[4]/b1[4], reloaded right after last use) bounds regs at 32.
//   - LDS = 64KB A-tile + 2.3KB stats = 68KB -> 2 blocks/CU, 16 waves/CU,
//     4 waves/SIMD (the TLP R4 lacked: 1 block/CU, 80% stall).
//   - __launch_bounds__(512,4) pins the 128-reg occupancy cliff.
//     Budget: acc 64 + b 32 + af 8 + addr ~16 = ~120.
//   - A resident/swizzled, LN in-block, fp16 wave-contiguous residual (nt),
//     all verified in R3/R4 (absmax 0.079).
// ---------------------------------------------------------------------------
__global__ __launch_bounds__(512, 4) void chain(
    const float* __restrict__ X,     // (N,F) fp32 input
    const u16* __restrict__ WT,      // (L, 2048 groups, 64 lanes, 8) bf16 packed
    const float* __restrict__ Bias,  // (L,F) fp32
    _Float16* __restrict__ Hf,       // fp16 residual ws, wave-contiguous
    float* __restrict__ Out,         // (N,F) fp32 output
    int N, int L)
{
    constexpr int F = 1024;
    constexpr int K = 1024;
    constexpr int ROWS = 32;
    extern __shared__ char smem[];
    // [0,65536): A tile [32][1024] bf16, swizzled
    float* wsS = (float*)(smem + 65536);   // [8][32]
    float* wsQ = (float*)(smem + 66560);   // [8][32]
    float* mr  = (float*)(smem + 67584);   // [32][2] mean,rstd

    const int tid  = threadIdx.x;
    const int w    = tid >> 6;        // wave 0..7 -> cols [128w,128w+128)
    const int lane = tid & 63;
    const int q    = lane >> 4;       // 0..3
    const int r16  = lane & 15;
    const int s3   = r16 & 7;         // A-swizzle key
    const int r0   = blockIdx.x * ROWS;

    const size_t ff = (size_t)F * K;

    // ---- stage A from X (fp32 -> bf16, swizzled), coalesced float4 ----
    {
        const float4* Xv = (const float4*)(X + (size_t)r0 * F);
#pragma unroll 4
        for (int i = 0; i < 16; ++i) {
            int e4 = i * 512 + tid;            // 0..8191
            float4 v = Xv[e4];
            int el  = e4 * 4;
            int row = el >> 10;
            int col = el & 1023;
            int chunk = (col >> 3) ^ (row & 7);
            int boff  = row * 2048 + chunk * 16 + (col & 7) * 2;
            ushort4 pk;
            pk.x = f2b(v.x); pk.y = f2b(v.y); pk.z = f2b(v.z); pk.w = f2b(v.w);
            *(ushort4*)(smem + boff) = pk;
        }
    }
    __syncthreads();

    const int aB0 = r16 * 2048;            // row r16      (rows 0..15)
    const int aB1 = (16 + r16) * 2048;     // row 16+r16

    // packed-B element offsets (within a layer): group (w*8+ni), this lane.
    unsigned int bOff[8];
#pragma unroll
    for (int ni = 0; ni < 8; ++ni)
        bOff[ni] = (unsigned int)(((w * 8 + ni) * 64 + lane) * 8);
    // kp stride = 64 groups * 64 lanes * 8 = 32768 elems

    // Hf: [block][wave][8 j][64 lanes][8 elems]
    const size_t hb = (size_t)blockIdx.x * (512 * 64) + (size_t)w * 4096
                    + (size_t)lane * 8;

    for (int l = 0; l < L; ++l) {
        const u16* wt = WT + (size_t)l * ff;

        f32x4 acc[2][8];
        const f32x4 zero = {0.f, 0.f, 0.f, 0.f};
#pragma unroll
        for (int mi = 0; mi < 2; ++mi)
#pragma unroll
            for (int ni = 0; ni < 8; ++ni) acc[mi][ni] = zero;

        bf16x8 b0[4], b1[4];
#pragma unroll
        for (int i = 0; i < 4; ++i) b0[i] = *(const bf16x8*)(wt + bOff[i]);
#pragma unroll
        for (int i = 0; i < 4; ++i) b1[i] = *(const bf16x8*)(wt + bOff[4 + i]);

        for (int kp = 0; kp < 32; ++kp) {
            const int kc = kp * 4 + q;
            const bf16x8 af0 = *(const bf16x8*)(smem + aB0 + ((kc ^ s3) << 4));
            const bf16x8 af1 = *(const bf16x8*)(smem + aB1 + ((kc ^ s3) << 4));
            const u16* nxt = wt + (((kp + 1) & 31) << 15);  // *32768

            __builtin_amdgcn_s_setprio(1);
#pragma unroll
            for (int i = 0; i < 4; ++i) {
                acc[0][i] = __builtin_amdgcn_mfma_f32_16x16x32_bf16(
                    af0, b0[i], acc[0][i], 0, 0, 0);
                acc[1][i] = __builtin_amdgcn_mfma_f32_16x16x32_bf16(
                    af1, b0[i], acc[1][i], 0, 0, 0);
            }
            __builtin_amdgcn_s_setprio(0);
#pragma unroll
            for (int i = 0; i < 4; ++i)          // reload right after last use
                b0[i] = *(const bf16x8*)(nxt + bOff[i]);

            __builtin_amdgcn_s_setprio(1);
#pragma unroll
            for (int i = 0; i < 4; ++i) {
                acc[0][4 + i] = __builtin_amdgcn_mfma_f32_16x16x32_bf16(
                    af0, b1[i], acc[0][4 + i], 0, 0, 0);
                acc[1][4 + i] = __builtin_amdgcn_mfma_f32_16x16x32_bf16(
                    af1, b1[i], acc[1][4 + i], 0, 0, 0);
            }
            __builtin_amdgcn_s_setprio(0);
#pragma unroll
            for (int i = 0; i < 4; ++i)
                b1[i] = *(const bf16x8*)(nxt + bOff[4 + i]);
        }

        // ---- epilogue: bias + relu + residual (fp32 math) ----
        // col(ni) = w*128 + ni*16 + r16
        float bv[8];
#pragma unroll
        for (int ni = 0; ni < 8; ++ni)
            bv[ni] = Bias[(size_t)l * F + w * 128 + ni * 16 + r16];

        if (l == 0) {
#pragma unroll
            for (int mi = 0; mi < 2; ++mi) {
                const int rl = mi * 16 + q * 4;
#pragma unroll
                for (int ni = 0; ni < 8; ++ni) {
                    const int cl = w * 128 + ni * 16 + r16;
                    const size_t g = (size_t)(r0 + rl) * F + cl;
#pragma unroll
                    for (int j = 0; j < 4; ++j) {
                        float h = X[g + (size_t)j * F];
                        acc[mi][ni][j] = fmaxf(acc[mi][ni][j] + bv[ni], 0.f) + h;
                    }
                }
            }
        } else {
#pragma unroll
            for (int j = 0; j < 8; ++j) {
                f16x8 v = __builtin_nontemporal_load(
                    (const f16x8*)(Hf + hb + j * 512));
#pragma unroll
                for (int half = 0; half < 2; ++half) {
                    const int c  = j * 2 + half;
                    const int mi = c >> 3, ni = c & 7;
#pragma unroll
                    for (int jj = 0; jj < 4; ++jj) {
                        float h = (float)v[half * 4 + jj];
                        acc[mi][ni][jj] =
                            fmaxf(acc[mi][ni][jj] + bv[ni], 0.f) + h;
                    }
                }
            }
        }

        // ---- LN stats ----
        float sS[2][4], sQ[2][4];
#pragma unroll
        for (int mi = 0; mi < 2; ++mi)
#pragma unroll
            for (int j = 0; j < 4; ++j) {
                float s = 0.f, s2 = 0.f;
#pragma unroll
                for (int ni = 0; ni < 8; ++ni) {
                    float y = acc[mi][ni][j];
                    s += y; s2 = fmaf(y, y, s2);
                }
#pragma unroll
                for (int m = 1; m < 16; m <<= 1) {
                    s  += __shfl_xor(s,  m, 64);
                    s2 += __shfl_xor(s2, m, 64);
                }
                sS[mi][j] = s; sQ[mi][j] = s2;
            }

        if (r16 == 0) {
#pragma unroll
            for (int mi = 0; mi < 2; ++mi)
#pragma unroll
                for (int j = 0; j < 4; ++j) {
                    int row = mi * 16 + q * 4 + j;
                    wsS[w * 32 + row] = sS[mi][j];
                    wsQ[w * 32 + row] = sQ[mi][j];
                }
        }
        __syncthreads();   // also: all waves done reading A this layer
        if (tid < 32) {
            float s = 0.f, s2 = 0.f;
#pragma unroll
            for (int ww = 0; ww < 8; ++ww) {
                s  += wsS[ww * 32 + tid];
                s2 += wsQ[ww * 32 + tid];
            }
            float mean = s * (1.f / 1024.f);
            float var  = s2 * (1.f / 1024.f) - mean * mean;
            mr[tid * 2]     = mean;
            mr[tid * 2 + 1] = rsqrtf(var + LN_EPS);
        }
        __syncthreads();

        float mean_[2][4], rstd_[2][4];
#pragma unroll
        for (int mi = 0; mi < 2; ++mi)
#pragma unroll
            for (int j = 0; j < 4; ++j) {
                int row = mi * 16 + q * 4 + j;
                mean_[mi][j] = mr[row * 2];
                rstd_[mi][j] = mr[row * 2 + 1];
            }

        // ---- normalize; write next-h (A LDS + Hf nt) or final Out (nt) ----
        if (l == L - 1) {
#pragma unroll
            for (int mi = 0; mi < 2; ++mi)
#pragma unroll
                for (int ni = 0; ni < 8; ++ni) {
                    const int cl = w * 128 + ni * 16 + r16;
#pragma unroll
                    for (int j = 0; j < 4; ++j) {
                        const int row = mi * 16 + q * 4 + j;
                        float yn = (acc[mi][ni][j] - mean_[mi][j]) * rstd_[mi][j];
                        __builtin_nontemporal_store(
                            yn, Out + (size_t)(r0 + row) * F + cl);
                    }
                }
        } else {
            _Float16 hbuf[64];
#pragma unroll
            for (int mi = 0; mi < 2; ++mi)
#pragma unroll
                for (int ni = 0; ni < 8; ++ni) {
                    const int cl = w * 128 + ni * 16 + r16;
#pragma unroll
                    for (int j = 0; j < 4; ++j) {
                        const int row = mi * 16 + q * 4 + j;
                        float yn = (acc[mi][ni][j] - mean_[mi][j]) * rstd_[mi][j];
                        hbuf[(mi * 8 + ni) * 4 + j] = (_Float16)yn;
                        int chunk = (cl >> 3) ^ (row & 7);
                        int boff  = row * 2048 + chunk * 16 + (cl & 7) * 2;
                        *(u16*)(smem + boff) = f2b(yn);
                    }
                }
#pragma unroll
            for (int j = 0; j < 8; ++j)
                __builtin_nontemporal_store(
                    *(const f16x8*)(hbuf + j * 8), (f16x8*)(Hf + hb + j * 512));
        }
        __syncthreads();   // A rewritten + mr consumed before next layer
    }
}

// ---------------------------------------------------------------------------
extern "C" void kernel_launch(void* const* d_in, const int* in_sizes, int n_in,
                              void* d_out, int out_size, void* d_ws, size_t ws_size,
                              hipStream_t stream) {
    const float* x    = (const float*)d_in[0];   // fp32 (N,F)
    const float* adj  = (const float*)d_in[1];   // fp32 (F,F)
    const float* W    = (const float*)d_in[2];   // fp32 (L,F,F)
    const float* bias = (const float*)d_in[3];   // fp32 (L,F)
    float* out = (float*)d_out;                  // fp32 (N,F)

    const int L = in_sizes[2] / in_sizes[1];     // 5
    const int F = in_sizes[3] / L;               // 1024
    const int N = in_sizes[0] / F;               // 16384

    const size_t ff = (size_t)F * F;

    // ws: WT packed (L*ff bf16, 10.5 MB) + Hf fp16 residual (N*F*2 = 33.6 MB)
    u16* WT = (u16*)d_ws;
    _Float16* Hf = (_Float16*)((char*)d_ws + (size_t)L * ff * sizeof(u16));

    prep_weights<<<dim3(F / 64, F / 64, L), 256, 0, stream>>>(W, adj, WT, F);

    constexpr unsigned SMEM = 67840;  // 64KB A + 2KB stats + 256B mean/rstd
    static bool attrSet = false;
    if (!attrSet) {
        (void)hipFuncSetAttribute(reinterpret_cast<const void*>(chain),
                                  hipFuncAttributeMaxDynamicSharedMemorySize,
                                  (int)SMEM);
        attrSet = true;
    }
    chain<<<N / 32, 512, SMEM, stream>>>(x, WT, bias, Hf, out, N, L);
}